// Round 1
// baseline (95869.946 us; speedup 1.0000x reference)
//
#include <hip/hip_runtime.h>

#define Bsz 16
#define Lsz 512
#define Dsz 1024
#define NLayers 4

// ---------------- zero flags ----------------
__global__ void zero_flags_kernel(int* flags) {
  flags[threadIdx.x] = 0;
}

// ---------------- transpose Wh: WhT[d][e] = W[e][Dsz + d] ----------------
__global__ void transpose_wh_kernel(const float* __restrict__ Wl, float* __restrict__ WhT) {
  __shared__ float tile[32][33];
  int e0 = blockIdx.x * 32;
  int d0 = blockIdx.y * 32;
  int tx = threadIdx.x;   // 0..31
  int ty = threadIdx.y;   // 0..7
#pragma unroll
  for (int r = ty; r < 32; r += 8)
    tile[r][tx] = Wl[(size_t)(e0 + r) * (2 * Dsz) + Dsz + d0 + tx];
  __syncthreads();
#pragma unroll
  for (int r = ty; r < 32; r += 8)
    WhT[(size_t)(d0 + r) * Dsz + e0 + tx] = tile[tx][r];
}

// ---------------- GEMM: Xw[m][e] = sum_k X[m][k] * Wl[e][k] + bias[e] ----------------
// M = B*L = 8192, N = D = 1024, K = D = 1024. 64x64 tiles, BK=16, 256 thr, 4x4/thread.
__global__ void __launch_bounds__(256) gemm_xw_kernel(
    const float* __restrict__ X, const float* __restrict__ Wl,
    const float* __restrict__ bias, float* __restrict__ Xw) {
  __shared__ float As[16][68];
  __shared__ float Bs[16][68];
  const int m0 = blockIdx.x * 64;
  const int n0 = blockIdx.y * 64;
  const int tid = threadIdx.x;
  const int tn = tid & 15, tm = tid >> 4;   // tn fast -> coalesced C stores
  const int r = tid >> 2, q = tid & 3;
  float acc[4][4] = {{0.f}};
  for (int k0 = 0; k0 < Dsz; k0 += 16) {
    float4 av = *(const float4*)(X  + (size_t)(m0 + r) * Dsz       + k0 + q * 4);
    float4 bv = *(const float4*)(Wl + (size_t)(n0 + r) * (2 * Dsz) + k0 + q * 4);
    __syncthreads();
    As[q*4+0][r] = av.x; As[q*4+1][r] = av.y; As[q*4+2][r] = av.z; As[q*4+3][r] = av.w;
    Bs[q*4+0][r] = bv.x; Bs[q*4+1][r] = bv.y; Bs[q*4+2][r] = bv.z; Bs[q*4+3][r] = bv.w;
    __syncthreads();
#pragma unroll
    for (int k = 0; k < 16; ++k) {
      float4 a = *(const float4*)&As[k][tm * 4];
      float4 b = *(const float4*)&Bs[k][tn * 4];
      acc[0][0] += a.x*b.x; acc[0][1] += a.x*b.y; acc[0][2] += a.x*b.z; acc[0][3] += a.x*b.w;
      acc[1][0] += a.y*b.x; acc[1][1] += a.y*b.y; acc[1][2] += a.y*b.z; acc[1][3] += a.y*b.w;
      acc[2][0] += a.z*b.x; acc[2][1] += a.z*b.y; acc[2][2] += a.z*b.z; acc[2][3] += a.z*b.w;
      acc[3][0] += a.w*b.x; acc[3][1] += a.w*b.y; acc[3][2] += a.w*b.z; acc[3][3] += a.w*b.w;
    }
  }
  float4 b4 = *(const float4*)(bias + n0 + tn * 4);
#pragma unroll
  for (int i = 0; i < 4; ++i) {
    float4 c;
    c.x = acc[i][0] + b4.x; c.y = acc[i][1] + b4.y;
    c.z = acc[i][2] + b4.z; c.w = acc[i][3] + b4.w;
    *(float4*)(Xw + (size_t)(m0 + tm * 4 + i) * Dsz + n0 + tn * 4) = c;
  }
}

// ---------------- scan: per-step h' = tanh(Xw[:,t,:] + h @ Wh^T) ----------------
// Grid: 256 WGs = 4 b-groups (4 batch rows each) x 64 e-slices (16 outputs each).
// Cluster = 64 WGs sharing a b-group; per-step flag handshake through L2.
__global__ void __launch_bounds__(256) scan_kernel(
    const float* __restrict__ WhT,   // [D][D] : WhT[d][e] = Wh[e][d]
    const float* __restrict__ Xw,    // [B][L][D]
    const float* __restrict__ h0,    // [B][D]   (this layer's h0 slice)
    float* __restrict__ H,           // [B][L][D] (d_out, also next layer's X)
    float* __restrict__ hping,       // [2][B][D]
    int* flags, int layer) {
  const int wg = blockIdx.x;
  const int bg = wg >> 6;          // 0..3
  const int sl = wg & 63;          // 0..63
  const int e0 = sl << 4;
  const int tid = threadIdx.x;
  const int ks = tid >> 4;         // 0..15  K-split
  const int bl = (tid >> 2) & 3;   // 0..3   batch-within-group
  const int eq = tid & 3;          // 0..3   e-quad
  const int b0 = bg << 2;

  __shared__ float h_lds[64][68];    // row = bl*16+ks, 64 d each (stride 68 kills conflicts)
  __shared__ float red[16][4][17];   // K-split partials

  const int base = layer * (Lsz - 1);   // 511 signals per layer, monotonic across layers

  for (int t = 0; t < Lsz; ++t) {
    // ---- stage h (4 rows x 1024 fp32 = 16KB) into LDS ----
    const float* hsrc = (t == 0)
        ? (h0 + (size_t)b0 * Dsz)
        : (hping + (size_t)((t + 1) & 1) * Bsz * Dsz + (size_t)b0 * Dsz);
    const float4* hs4 = (const float4*)hsrc;
#pragma unroll
    for (int i = tid; i < 1024; i += 256) {
      float4 v = hs4[i];
      int blx = i >> 8;          // which of 4 batch rows
      int d4  = i & 255;         // float4 index in row
      int ksx = d4 >> 4;
      int j4  = d4 & 15;
      *((float4*)&h_lds[(blx << 4) + ksx][j4 << 2]) = v;
    }
    __syncthreads();

    // ---- partial matvec: 4 e-outputs over 64 d's ----
    float a0 = 0.f, a1 = 0.f, a2 = 0.f, a3 = 0.f;
    const float* wb = WhT + e0 + (eq << 2);
    const int row = (bl << 4) + ks;
    const int dbase = ks << 6;
#pragma unroll 4
    for (int it = 0; it < 16; ++it) {
      float4 hv = *(const float4*)&h_lds[row][it << 2];
      const float* wp = wb + (size_t)(dbase + (it << 2)) * Dsz;
      float4 w0 = *(const float4*)(wp);
      float4 w1 = *(const float4*)(wp + Dsz);
      float4 w2 = *(const float4*)(wp + 2 * Dsz);
      float4 w3 = *(const float4*)(wp + 3 * Dsz);
      a0 += hv.x * w0.x + hv.y * w1.x + hv.z * w2.x + hv.w * w3.x;
      a1 += hv.x * w0.y + hv.y * w1.y + hv.z * w2.y + hv.w * w3.y;
      a2 += hv.x * w0.z + hv.y * w1.z + hv.z * w2.z + hv.w * w3.z;
      a3 += hv.x * w0.w + hv.y * w1.w + hv.z * w2.w + hv.w * w3.w;
    }
    red[ks][bl][(eq << 2) + 0] = a0;
    red[ks][bl][(eq << 2) + 1] = a1;
    red[ks][bl][(eq << 2) + 2] = a2;
    red[ks][bl][(eq << 2) + 3] = a3;
    __syncthreads();

    // ---- reduce K-split, add Xw, tanh, write out ----
    if (tid < 64) {
      const int bl2 = tid >> 4, el = tid & 15;
      float s = 0.f;
#pragma unroll
      for (int k2 = 0; k2 < 16; ++k2) s += red[k2][bl2][el];
      const int b = b0 + bl2, e = e0 + el;
      const size_t off = ((size_t)b * Lsz + t) * Dsz + e;
      const float hn = tanhf(s + Xw[off]);
      H[off] = hn;
      if (t < Lsz - 1)
        hping[(size_t)(t & 1) * Bsz * Dsz + (size_t)b * Dsz + e] = hn;
    }

    // ---- cluster barrier (release writes, signal, poll 64 flags, acquire) ----
    if (t < Lsz - 1) {
      __threadfence();
      __syncthreads();
      if (tid == 0)
        __hip_atomic_store(&flags[(bg << 6) + sl], base + t + 1,
                           __ATOMIC_RELEASE, __HIP_MEMORY_SCOPE_AGENT);
      if (tid < 64) {
        const int target = base + t + 1;
        int v;
        do {
          v = __hip_atomic_load(&flags[(bg << 6) + tid],
                                __ATOMIC_ACQUIRE, __HIP_MEMORY_SCOPE_AGENT);
        } while (!__all(v >= target));
      }
      __syncthreads();
      __threadfence();   // acquire side: make peers' hping stores visible to all waves
    }
  }
}

extern "C" void kernel_launch(void* const* d_in, const int* in_sizes, int n_in,
                              void* d_out, int out_size, void* d_ws, size_t ws_size,
                              hipStream_t stream) {
  (void)in_sizes; (void)n_in; (void)out_size; (void)ws_size;
  const float* X0   = (const float*)d_in[0];
  const float* h0s  = (const float*)d_in[1];
  const float* W    = (const float*)d_in[2];
  const float* bias = (const float*)d_in[3];
  float* out = (float*)d_out;
  char* ws = (char*)d_ws;
  // ws layout (needs ~37.9 MB): Xw 32MB | WhT 4MB | hping 128KB | flags 1KB
  float* Xw    = (float*)ws;
  float* WhT   = (float*)(ws + (size_t)33554432);
  float* hping = (float*)(ws + (size_t)33554432 + 4194304);
  int*   flags = (int*)  (ws + (size_t)33554432 + 4194304 + 131072);

  hipLaunchKernelGGL(zero_flags_kernel, dim3(1), dim3(256), 0, stream, flags);
  for (int i = 0; i < NLayers; ++i) {
    const float* Xin = (i == 0) ? X0 : out;           // previous layer's H feeds next GEMM
    const float* Wl  = W + (size_t)i * Dsz * 2 * Dsz;
    hipLaunchKernelGGL(transpose_wh_kernel, dim3(32, 32), dim3(32, 8), 0, stream, Wl, WhT);
    hipLaunchKernelGGL(gemm_xw_kernel, dim3(128, 16), dim3(256), 0, stream,
                       Xin, Wl, bias + (size_t)i * Dsz, Xw);
    hipLaunchKernelGGL(scan_kernel, dim3(256), dim3(256), 0, stream,
                       WhT, Xw, h0s + (size_t)i * Bsz * Dsz, out, hping, flags, i);
  }
}

// Round 2
// 33505.115 us; speedup vs baseline: 2.8614x; 2.8614x over previous
//
#include <hip/hip_runtime.h>

#define Bsz 16
#define Lsz 512
#define Dsz 1024
#define NLayers 4

// ---------------- zero flags ----------------
__global__ void zero_flags_kernel(int* flags) {
  flags[threadIdx.x] = 0;
}

// ---------------- transpose Wh: WhT[d][e] = W[e][Dsz + d] ----------------
__global__ void transpose_wh_kernel(const float* __restrict__ Wl, float* __restrict__ WhT) {
  __shared__ float tile[32][33];
  int e0 = blockIdx.x * 32;
  int d0 = blockIdx.y * 32;
  int tx = threadIdx.x;   // 0..31
  int ty = threadIdx.y;   // 0..7
#pragma unroll
  for (int r = ty; r < 32; r += 8)
    tile[r][tx] = Wl[(size_t)(e0 + r) * (2 * Dsz) + Dsz + d0 + tx];
  __syncthreads();
#pragma unroll
  for (int r = ty; r < 32; r += 8)
    WhT[(size_t)(d0 + r) * Dsz + e0 + tx] = tile[tx][r];
}

// ---------------- GEMM: Xw[m][e] = sum_k X[m][k] * Wl[e][k] + bias[e] ----------------
// M = B*L = 8192, N = D = 1024, K = D = 1024. 64x64 tiles, BK=16, 256 thr, 4x4/thread.
__global__ void __launch_bounds__(256) gemm_xw_kernel(
    const float* __restrict__ X, const float* __restrict__ Wl,
    const float* __restrict__ bias, float* __restrict__ Xw) {
  __shared__ float As[16][68];
  __shared__ float Bs[16][68];
  const int m0 = blockIdx.x * 64;
  const int n0 = blockIdx.y * 64;
  const int tid = threadIdx.x;
  const int tn = tid & 15, tm = tid >> 4;   // tn fast -> coalesced C stores
  const int r = tid >> 2, q = tid & 3;
  float acc[4][4] = {{0.f}};
  for (int k0 = 0; k0 < Dsz; k0 += 16) {
    float4 av = *(const float4*)(X  + (size_t)(m0 + r) * Dsz       + k0 + q * 4);
    float4 bv = *(const float4*)(Wl + (size_t)(n0 + r) * (2 * Dsz) + k0 + q * 4);
    __syncthreads();
    As[q*4+0][r] = av.x; As[q*4+1][r] = av.y; As[q*4+2][r] = av.z; As[q*4+3][r] = av.w;
    Bs[q*4+0][r] = bv.x; Bs[q*4+1][r] = bv.y; Bs[q*4+2][r] = bv.z; Bs[q*4+3][r] = bv.w;
    __syncthreads();
#pragma unroll
    for (int k = 0; k < 16; ++k) {
      float4 a = *(const float4*)&As[k][tm * 4];
      float4 b = *(const float4*)&Bs[k][tn * 4];
      acc[0][0] += a.x*b.x; acc[0][1] += a.x*b.y; acc[0][2] += a.x*b.z; acc[0][3] += a.x*b.w;
      acc[1][0] += a.y*b.x; acc[1][1] += a.y*b.y; acc[1][2] += a.y*b.z; acc[1][3] += a.y*b.w;
      acc[2][0] += a.z*b.x; acc[2][1] += a.z*b.y; acc[2][2] += a.z*b.z; acc[2][3] += a.z*b.w;
      acc[3][0] += a.w*b.x; acc[3][1] += a.w*b.y; acc[3][2] += a.w*b.z; acc[3][3] += a.w*b.w;
    }
  }
  float4 b4 = *(const float4*)(bias + n0 + tn * 4);
#pragma unroll
  for (int i = 0; i < 4; ++i) {
    float4 c;
    c.x = acc[i][0] + b4.x; c.y = acc[i][1] + b4.y;
    c.z = acc[i][2] + b4.z; c.w = acc[i][3] + b4.w;
    *(float4*)(Xw + (size_t)(m0 + tm * 4 + i) * Dsz + n0 + tn * 4) = c;
  }
}

// ---------------- scan: per-step h' = tanh(Xw[:,t,:] + h @ Wh^T) ----------------
// Grid: 256 WGs = 4 b-groups (4 batch rows each) x 64 e-slices (16 outputs each).
// Cluster = 64 WGs sharing a b-group; per-step flag handshake through IF$.
// Sync protocol (the round-1 fix):
//   - tid0 RELEASE-stores its flag (one buffer_wbl2 per WG per step publishes
//     this wave's H/hping stores; tid<64 all live in wave 0).
//   - wave 0 polls peers' flags with RELAXED agent loads (no buffer_inv per
//     poll!) + s_sleep backoff.
//   - after the post-poll barrier, ONE acquire fence (buffer_inv) per wave
//     makes peers' hping stores visible.
__global__ void __launch_bounds__(256) scan_kernel(
    const float* __restrict__ WhT,   // [D][D] : WhT[d][e] = Wh[e][d]
    const float* __restrict__ Xw,    // [B][L][D]
    const float* __restrict__ h0,    // [B][D]   (this layer's h0 slice)
    float* __restrict__ H,           // [B][L][D] (d_out, also next layer's X)
    float* __restrict__ hping,       // [2][B][D]
    int* flags, int layer) {
  const int wg = blockIdx.x;
  const int bg = wg >> 6;          // 0..3
  const int sl = wg & 63;          // 0..63
  const int e0 = sl << 4;
  const int tid = threadIdx.x;
  const int ks = tid >> 4;         // 0..15  K-split
  const int bl = (tid >> 2) & 3;   // 0..3   batch-within-group
  const int eq = tid & 3;          // 0..3   e-quad
  const int b0 = bg << 2;

  __shared__ float h_lds[64][68];    // row = bl*16+ks, 64 d each (stride 68 kills conflicts)
  __shared__ float red[16][4][17];   // K-split partials

  const int base = layer * (Lsz - 1);   // 511 signals per layer, monotonic across layers

  for (int t = 0; t < Lsz; ++t) {
    // ---- stage h (4 rows x 1024 fp32 = 16KB) into LDS ----
    const float* hsrc = (t == 0)
        ? (h0 + (size_t)b0 * Dsz)
        : (hping + (size_t)((t + 1) & 1) * Bsz * Dsz + (size_t)b0 * Dsz);
    const float4* hs4 = (const float4*)hsrc;
#pragma unroll
    for (int i = tid; i < 1024; i += 256) {
      float4 v = hs4[i];
      int blx = i >> 8;          // which of 4 batch rows
      int d4  = i & 255;         // float4 index in row
      int ksx = d4 >> 4;
      int j4  = d4 & 15;
      *((float4*)&h_lds[(blx << 4) + ksx][j4 << 2]) = v;
    }
    __syncthreads();

    // ---- partial matvec: 4 e-outputs over 64 d's ----
    float a0 = 0.f, a1 = 0.f, a2 = 0.f, a3 = 0.f;
    const float* wb = WhT + e0 + (eq << 2);
    const int row = (bl << 4) + ks;
    const int dbase = ks << 6;
#pragma unroll 4
    for (int it = 0; it < 16; ++it) {
      float4 hv = *(const float4*)&h_lds[row][it << 2];
      const float* wp = wb + (size_t)(dbase + (it << 2)) * Dsz;
      float4 w0 = *(const float4*)(wp);
      float4 w1 = *(const float4*)(wp + Dsz);
      float4 w2 = *(const float4*)(wp + 2 * Dsz);
      float4 w3 = *(const float4*)(wp + 3 * Dsz);
      a0 += hv.x * w0.x + hv.y * w1.x + hv.z * w2.x + hv.w * w3.x;
      a1 += hv.x * w0.y + hv.y * w1.y + hv.z * w2.y + hv.w * w3.y;
      a2 += hv.x * w0.z + hv.y * w1.z + hv.z * w2.z + hv.w * w3.z;
      a3 += hv.x * w0.w + hv.y * w1.w + hv.z * w2.w + hv.w * w3.w;
    }
    red[ks][bl][(eq << 2) + 0] = a0;
    red[ks][bl][(eq << 2) + 1] = a1;
    red[ks][bl][(eq << 2) + 2] = a2;
    red[ks][bl][(eq << 2) + 3] = a3;
    __syncthreads();

    // ---- reduce K-split, add Xw, tanh, write out (tid<64 == wave 0 only) ----
    if (tid < 64) {
      const int bl2 = tid >> 4, el = tid & 15;
      float s = 0.f;
#pragma unroll
      for (int k2 = 0; k2 < 16; ++k2) s += red[k2][bl2][el];
      const int b = b0 + bl2, e = e0 + el;
      const size_t off = ((size_t)b * Lsz + t) * Dsz + e;
      const float hn = tanhf(s + Xw[off]);
      H[off] = hn;
      if (t < Lsz - 1)
        hping[(size_t)(t & 1) * Bsz * Dsz + (size_t)b * Dsz + e] = hn;
    }

    // ---- cluster barrier ----
    if (t < Lsz - 1) {
      // Signal: RELEASE store by tid0 (wave 0 — the same wave that wrote
      // hping/H above, so the release orders those stores; single wbl2).
      if (tid == 0)
        __hip_atomic_store(&flags[(bg << 6) + sl], base + t + 1,
                           __ATOMIC_RELEASE, __HIP_MEMORY_SCOPE_AGENT);
      // Poll: RELAXED loads, one flag per lane, s_sleep backoff.
      if (tid < 64) {
        const int target = base + t + 1;
        for (;;) {
          int v = __hip_atomic_load(&flags[(bg << 6) + tid],
                                    __ATOMIC_RELAXED, __HIP_MEMORY_SCOPE_AGENT);
          if (__all(v >= target)) break;
          __builtin_amdgcn_s_sleep(1);
        }
      }
      __syncthreads();
      // One acquire per wave: invalidate stale L1/L2 lines so next staging
      // read of hping sees peers' stores.
      __builtin_amdgcn_fence(__ATOMIC_ACQUIRE, "agent");
    }
  }
}

extern "C" void kernel_launch(void* const* d_in, const int* in_sizes, int n_in,
                              void* d_out, int out_size, void* d_ws, size_t ws_size,
                              hipStream_t stream) {
  (void)in_sizes; (void)n_in; (void)out_size; (void)ws_size;
  const float* X0   = (const float*)d_in[0];
  const float* h0s  = (const float*)d_in[1];
  const float* W    = (const float*)d_in[2];
  const float* bias = (const float*)d_in[3];
  float* out = (float*)d_out;
  char* ws = (char*)d_ws;
  // ws layout (needs ~37.9 MB): Xw 32MB | WhT 4MB | hping 128KB | flags 1KB
  float* Xw    = (float*)ws;
  float* WhT   = (float*)(ws + (size_t)33554432);
  float* hping = (float*)(ws + (size_t)33554432 + 4194304);
  int*   flags = (int*)  (ws + (size_t)33554432 + 4194304 + 131072);

  hipLaunchKernelGGL(zero_flags_kernel, dim3(1), dim3(256), 0, stream, flags);
  for (int i = 0; i < NLayers; ++i) {
    const float* Xin = (i == 0) ? X0 : out;           // previous layer's H feeds next GEMM
    const float* Wl  = W + (size_t)i * Dsz * 2 * Dsz;
    hipLaunchKernelGGL(transpose_wh_kernel, dim3(32, 32), dim3(32, 8), 0, stream, Wl, WhT);
    hipLaunchKernelGGL(gemm_xw_kernel, dim3(128, 16), dim3(256), 0, stream,
                       Xin, Wl, bias + (size_t)i * Dsz, Xw);
    hipLaunchKernelGGL(scan_kernel, dim3(256), dim3(256), 0, stream,
                       WhT, Xw, h0s + (size_t)i * Bsz * Dsz, out, hping, flags, i);
  }
}

// Round 3
// 20211.623 us; speedup vs baseline: 4.7433x; 1.6577x over previous
//
#include <hip/hip_runtime.h>

#define Bsz 16
#define Lsz 512
#define Dsz 1024
#define NLayers 4

// ---------------- zero flags (write-through atomics — no dirty L2 lines) ----------------
__global__ void zero_flags_kernel(int* flags) {
  __hip_atomic_store(&flags[threadIdx.x], 0, __ATOMIC_RELAXED, __HIP_MEMORY_SCOPE_AGENT);
}

// ---------------- transpose Wh: WhT[d][e] = W[e][Dsz + d] ----------------
__global__ void transpose_wh_kernel(const float* __restrict__ Wl, float* __restrict__ WhT) {
  __shared__ float tile[32][33];
  int e0 = blockIdx.x * 32;
  int d0 = blockIdx.y * 32;
  int tx = threadIdx.x;   // 0..31
  int ty = threadIdx.y;   // 0..7
#pragma unroll
  for (int r = ty; r < 32; r += 8)
    tile[r][tx] = Wl[(size_t)(e0 + r) * (2 * Dsz) + Dsz + d0 + tx];
  __syncthreads();
#pragma unroll
  for (int r = ty; r < 32; r += 8)
    WhT[(size_t)(d0 + r) * Dsz + e0 + tx] = tile[tx][r];
}

// ---------------- GEMM: Xw[m][e] = sum_k X[m][k] * Wl[e][k] + bias[e] ----------------
__global__ void __launch_bounds__(256) gemm_xw_kernel(
    const float* __restrict__ X, const float* __restrict__ Wl,
    const float* __restrict__ bias, float* __restrict__ Xw) {
  __shared__ float As[16][68];
  __shared__ float Bs[16][68];
  const int m0 = blockIdx.x * 64;
  const int n0 = blockIdx.y * 64;
  const int tid = threadIdx.x;
  const int tn = tid & 15, tm = tid >> 4;
  const int r = tid >> 2, q = tid & 3;
  float acc[4][4] = {{0.f}};
  for (int k0 = 0; k0 < Dsz; k0 += 16) {
    float4 av = *(const float4*)(X  + (size_t)(m0 + r) * Dsz       + k0 + q * 4);
    float4 bv = *(const float4*)(Wl + (size_t)(n0 + r) * (2 * Dsz) + k0 + q * 4);
    __syncthreads();
    As[q*4+0][r] = av.x; As[q*4+1][r] = av.y; As[q*4+2][r] = av.z; As[q*4+3][r] = av.w;
    Bs[q*4+0][r] = bv.x; Bs[q*4+1][r] = bv.y; Bs[q*4+2][r] = bv.z; Bs[q*4+3][r] = bv.w;
    __syncthreads();
#pragma unroll
    for (int k = 0; k < 16; ++k) {
      float4 a = *(const float4*)&As[k][tm * 4];
      float4 b = *(const float4*)&Bs[k][tn * 4];
      acc[0][0] += a.x*b.x; acc[0][1] += a.x*b.y; acc[0][2] += a.x*b.z; acc[0][3] += a.x*b.w;
      acc[1][0] += a.y*b.x; acc[1][1] += a.y*b.y; acc[1][2] += a.y*b.z; acc[1][3] += a.y*b.w;
      acc[2][0] += a.z*b.x; acc[2][1] += a.z*b.y; acc[2][2] += a.z*b.z; acc[2][3] += a.z*b.w;
      acc[3][0] += a.w*b.x; acc[3][1] += a.w*b.y; acc[3][2] += a.w*b.z; acc[3][3] += a.w*b.w;
    }
  }
  float4 b4 = *(const float4*)(bias + n0 + tn * 4);
#pragma unroll
  for (int i = 0; i < 4; ++i) {
    float4 c;
    c.x = acc[i][0] + b4.x; c.y = acc[i][1] + b4.y;
    c.z = acc[i][2] + b4.z; c.w = acc[i][3] + b4.w;
    *(float4*)(Xw + (size_t)(m0 + tm * 4 + i) * Dsz + n0 + tn * 4) = c;
  }
}

// ---------------- scan: per-step h' = tanh(Xw[:,t,:] + h @ Wh^T) ----------------
// Grid: 256 WGs = 4 b-groups x 64 e-slices. Cluster = 64 WGs sharing 4 batch rows.
// Round-3 sync protocol: ZERO cache-maintenance ops in the step loop.
//   - hping + flags are accessed ONLY via relaxed agent-scope atomics
//     (sc0 sc1: bypass L1/L2, read/write the coherence point directly).
//   - producer: data stores -> s_waitcnt vmcnt(0) -> flag store (MALL serializes).
//   - consumer: relaxed poll, then read data relaxed. No wbl2, no inv ->
//     WhT stays resident in each XCD's L2 for all 512 steps.
__global__ void __launch_bounds__(256) scan_kernel(
    const float* __restrict__ WhT,   // [D][D] : WhT[d][e] = Wh[e][d]
    const float* __restrict__ Xw,    // [B][L][D]
    const float* __restrict__ h0,    // [B][D]
    float* __restrict__ H,           // [B][L][D] (d_out)
    float* hping,                    // [2][B][D] (atomic write-through)
    int* flags, int layer) {
  const int wg = blockIdx.x;
  const int bg = wg >> 6;          // 0..3
  const int sl = wg & 63;          // 0..63
  const int e0 = sl << 4;
  const int tid = threadIdx.x;
  const int ks = tid >> 4;         // 0..15  K-split
  const int bl = (tid >> 2) & 3;   // 0..3   batch-within-group
  const int eq = tid & 3;          // 0..3   e-quad
  const int b0 = bg << 2;

  __shared__ float h_lds[64][68];
  __shared__ float red[16][4][17];

  const int base = layer * (Lsz - 1);

  for (int t = 0; t < Lsz; ++t) {
    // ---- stage h (4 rows x 1024 fp32 = 16KB) into LDS ----
    if (t == 0) {
      const float4* hs4 = (const float4*)(h0 + (size_t)b0 * Dsz);
#pragma unroll
      for (int i = tid; i < 1024; i += 256) {
        float4 v = hs4[i];
        int blx = i >> 8, d4 = i & 255;
        int ksx = d4 >> 4, j4 = d4 & 15;
        *((float4*)&h_lds[(blx << 4) + ksx][j4 << 2]) = v;
      }
    } else {
      const unsigned long long* hs8 = (const unsigned long long*)
          (hping + (size_t)((t + 1) & 1) * Bsz * Dsz + (size_t)b0 * Dsz);
#pragma unroll
      for (int i = tid; i < 2048; i += 256) {     // 2048 x 8B = 4 rows x 1024 f32
        unsigned long long v = __hip_atomic_load(&hs8[i],
            __ATOMIC_RELAXED, __HIP_MEMORY_SCOPE_AGENT);
        int blx = i >> 9;          // 512 ull per row
        int r8  = i & 511;         // ull index in row -> floats 2*r8, 2*r8+1
        int ksx = r8 >> 5;         // 32 ull per 64-float chunk
        int j8  = r8 & 31;
        union { unsigned long long u; float f[2]; } cv; cv.u = v;
        h_lds[(blx << 4) + ksx][(j8 << 1) + 0] = cv.f[0];
        h_lds[(blx << 4) + ksx][(j8 << 1) + 1] = cv.f[1];
      }
    }
    __syncthreads();

    // ---- partial matvec: 4 e-outputs over 64 d's ----
    float a0 = 0.f, a1 = 0.f, a2 = 0.f, a3 = 0.f;
    const float* wb = WhT + e0 + (eq << 2);
    const int row = (bl << 4) + ks;
    const int dbase = ks << 6;
#pragma unroll 4
    for (int it = 0; it < 16; ++it) {
      float4 hv = *(const float4*)&h_lds[row][it << 2];
      const float* wp = wb + (size_t)(dbase + (it << 2)) * Dsz;
      float4 w0 = *(const float4*)(wp);
      float4 w1 = *(const float4*)(wp + Dsz);
      float4 w2 = *(const float4*)(wp + 2 * Dsz);
      float4 w3 = *(const float4*)(wp + 3 * Dsz);
      a0 += hv.x * w0.x + hv.y * w1.x + hv.z * w2.x + hv.w * w3.x;
      a1 += hv.x * w0.y + hv.y * w1.y + hv.z * w2.y + hv.w * w3.y;
      a2 += hv.x * w0.z + hv.y * w1.z + hv.z * w2.z + hv.w * w3.z;
      a3 += hv.x * w0.w + hv.y * w1.w + hv.z * w2.w + hv.w * w3.w;
    }
    red[ks][bl][(eq << 2) + 0] = a0;
    red[ks][bl][(eq << 2) + 1] = a1;
    red[ks][bl][(eq << 2) + 2] = a2;
    red[ks][bl][(eq << 2) + 3] = a3;
    __syncthreads();

    // ---- reduce K-split, add Xw, tanh, write out (tid<64 == wave 0) ----
    if (tid < 64) {
      const int bl2 = tid >> 4, el = tid & 15;
      const int b = b0 + bl2, e = e0 + el;
      const size_t off = ((size_t)b * Lsz + t) * Dsz + e;
      const float xwv = Xw[off];          // independent load, issues early
      float s = 0.f;
#pragma unroll
      for (int k2 = 0; k2 < 16; ++k2) s += red[k2][bl2][el];
      const float hn = tanhf(s + xwv);
      H[off] = hn;                        // plain store (not read this dispatch)
      if (t < Lsz - 1) {
        unsigned* hp = (unsigned*)hping +
            (size_t)(t & 1) * Bsz * Dsz + (size_t)b * Dsz + e;
        __hip_atomic_store(hp, __float_as_uint(hn),
                           __ATOMIC_RELAXED, __HIP_MEMORY_SCOPE_AGENT);
      }
    }

    // ---- cluster barrier: waitcnt-ordered flag store + relaxed poll ----
    if (t < Lsz - 1) {
      if (tid < 64) {
        // Order this wave's hping write-through stores before the flag store.
        asm volatile("s_waitcnt vmcnt(0)" ::: "memory");
        if (tid == 0)
          __hip_atomic_store(&flags[(bg << 6) + sl], base + t + 1,
                             __ATOMIC_RELAXED, __HIP_MEMORY_SCOPE_AGENT);
        const int target = base + t + 1;
        for (;;) {
          int v = __hip_atomic_load(&flags[(bg << 6) + tid],
                                    __ATOMIC_RELAXED, __HIP_MEMORY_SCOPE_AGENT);
          if (__all(v >= target)) break;
          __builtin_amdgcn_s_sleep(1);
        }
      }
      __syncthreads();
    }
  }
}

extern "C" void kernel_launch(void* const* d_in, const int* in_sizes, int n_in,
                              void* d_out, int out_size, void* d_ws, size_t ws_size,
                              hipStream_t stream) {
  (void)in_sizes; (void)n_in; (void)out_size; (void)ws_size;
  const float* X0   = (const float*)d_in[0];
  const float* h0s  = (const float*)d_in[1];
  const float* W    = (const float*)d_in[2];
  const float* bias = (const float*)d_in[3];
  float* out = (float*)d_out;
  char* ws = (char*)d_ws;
  // ws layout (~37.9 MB): Xw 32MB | WhT 4MB | hping 128KB | flags 1KB
  float* Xw    = (float*)ws;
  float* WhT   = (float*)(ws + (size_t)33554432);
  float* hping = (float*)(ws + (size_t)33554432 + 4194304);
  int*   flags = (int*)  (ws + (size_t)33554432 + 4194304 + 131072);

  hipLaunchKernelGGL(zero_flags_kernel, dim3(1), dim3(256), 0, stream, flags);
  for (int i = 0; i < NLayers; ++i) {
    const float* Xin = (i == 0) ? X0 : out;
    const float* Wl  = W + (size_t)i * Dsz * 2 * Dsz;
    hipLaunchKernelGGL(transpose_wh_kernel, dim3(32, 32), dim3(32, 8), 0, stream, Wl, WhT);
    hipLaunchKernelGGL(gemm_xw_kernel, dim3(128, 16), dim3(256), 0, stream,
                       Xin, Wl, bias + (size_t)i * Dsz, Xw);
    hipLaunchKernelGGL(scan_kernel, dim3(256), dim3(256), 0, stream,
                       WhT, Xw, h0s + (size_t)i * Bsz * Dsz, out, hping, flags, i);
  }
}

// Round 6
// 3353.876 us; speedup vs baseline: 28.5848x; 6.0263x over previous
//
#include <hip/hip_runtime.h>

#define Bsz 16
#define Lsz 512
#define Dsz 1024
#define NL 4
#define NWG 64                    // 4 layers x 16 e-slices
#define ROUNDS (Lsz + NL - 1)     // 515

typedef unsigned short u16;
typedef unsigned long long u64;
typedef __attribute__((ext_vector_type(8))) short bf16x8;
typedef __attribute__((ext_vector_type(4))) float f32x4;

static __device__ __forceinline__ u16 f2bf(float x) {  // RNE, finite inputs
  unsigned u = __float_as_uint(x);
  return (u16)((u + 0x7fffu + ((u >> 16) & 1u)) >> 16);
}

__global__ void zero_flags_kernel(int* flags) {
  __hip_atomic_store(&flags[threadIdx.x], 0, __ATOMIC_RELAXED, __HIP_MEMORY_SCOPE_AGENT);
}

// flat fp32 -> bf16 (4 elems / iter)
__global__ void convert_bf16_kernel(const float* __restrict__ src, u16* __restrict__ dst, int n4) {
  int i = blockIdx.x * blockDim.x + threadIdx.x;
  int stride = gridDim.x * blockDim.x;
  for (; i < n4; i += stride) {
    float4 v = ((const float4*)src)[i];
    u64 p = (u64)f2bf(v.x) | ((u64)f2bf(v.y) << 16) |
            ((u64)f2bf(v.z) << 32) | ((u64)f2bf(v.w) << 48);
    ((u64*)dst)[i] = p;
  }
}

// h0s[l][b][d] -> hbuf[l][slot=1][b][d]  (t=0 reads slot (t-1)&1 = 1)
__global__ void init_h0_kernel(const float* __restrict__ h0s, u16* __restrict__ hbuf) {
  int i = blockIdx.x * blockDim.x + threadIdx.x;   // 16384 threads, 1 float4 each
  float4 v = ((const float4*)h0s)[i];
  u64 p = (u64)f2bf(v.x) | ((u64)f2bf(v.y) << 16) |
          ((u64)f2bf(v.z) << 32) | ((u64)f2bf(v.w) << 48);
  int l = i >> 12;          // 4096 float4 per layer (16*1024/4)
  int rem = i & 4095;
  ((u64*)hbuf)[(size_t)(l * 2 + 1) * 4096 + rem] = p;
}

// ---------------- persistent pipelined RNN ----------------
// 64 WGs x 1024 thr. WG wg: layer = wg>>4, e-slice = (wg&15)*64.
// Round r (1..515): layer l processes t = r-1-l.
//   h_l[t] = tanh( H_{l-1}[t] @ Wx^T + b + h_l[t-1] @ Wh^T )
// Per WG: 16 waves = 4 k-quarters x 4 n-subtiles; each wave: 16 MFMA
// (16x16x32 bf16, D[e16][b16]); W-fragments live in VGPRs for all 515 rounds.
// Cross-WG: bf16 h through MALL (relaxed agent atomics, write-through; the
// round-3-verified protocol), global 64-flag lockstep barrier per round.
__global__ void __launch_bounds__(1024, 4) rnn_persistent(
    const u16* __restrict__ Wbf,    // [NL][1024][2048]  (cols 0:1024=Wx, 1024:2048=Wh)
    const u16* __restrict__ Xbf,    // [Bsz][Lsz][Dsz]
    const float* __restrict__ bias, // [NL][Dsz]
    float* __restrict__ Hout,       // [Bsz][Lsz][Dsz]  (final layer only)
    u16* hbuf,                      // [NL][2][Bsz][Dsz]
    int* flags) {
  const int wg = blockIdx.x;
  const int layer = wg >> 4;
  const int e0 = (wg & 15) << 6;
  const int tid = threadIdx.x;
  const int w = tid >> 6;          // wave 0..15
  const int lane = tid & 63;
  const int kq = w >> 2;           // k-quarter (256 d)
  const int nt = w & 3;            // n-subtile (16 e)

  // LDS: h tiles [16 b][1024 d] bf16, XOR-swizzled in 8-u16 (16B) granules:
  // granule g of row b stored at g^(b&7)  -> conflict-free ds_read_b128.
  __shared__ u16 hA[16][1024];     // h_state
  __shared__ u16 hB[16][1024];     // prev-layer output (or X)
  __shared__ f32x4 red[16][64];    // k-split partials

  // ---- preload W fragments into VGPRs (time-invariant) ----
  bf16x8 wfh[8], wfx[8];
  {
    const int e = e0 + nt * 16 + (lane & 15);
    const u16* baseW = Wbf + ((size_t)((layer << 10) + e) << 11)  // *2048
                       + kq * 256 + ((lane >> 4) << 3);
#pragma unroll
    for (int s = 0; s < 8; ++s) {
      wfx[s] = *(const bf16x8*)(baseW + s * 32);          // Wx
      wfh[s] = *(const bf16x8*)(baseW + 1024 + s * 32);   // Wh
    }
  }
  // ---- epilogue constants (waves 0..3 reduce n-subtile nt=w) ----
  const int b_ep = lane & 15;
  const int e_ep = e0 + w * 16 + ((lane >> 4) << 2);
  float4 bias4 = {0.f, 0.f, 0.f, 0.f};
  if (w < 4) bias4 = *(const float4*)(bias + (layer << 10) + e_ep);

  const int klane = kq * 256 + ((lane >> 4) << 3);   // this lane's k base
  const int mrow = lane & 15;                        // b for B-frag / e-row for A

  for (int r = 1; r <= ROUNDS; ++r) {
    // ---- global lockstep: all 64 WGs finished round r-1 ----
    if (tid < 64) {
      const int tgt = r - 1;
      for (;;) {
        int v = __hip_atomic_load(&flags[tid], __ATOMIC_RELAXED, __HIP_MEMORY_SCOPE_AGENT);
        if (__all(v >= tgt)) break;
        __builtin_amdgcn_s_sleep(1);
      }
    }
    __syncthreads();

    const int t = r - 1 - layer;
    if (t >= 0 && t < Lsz) {
      // ---- stage h_state -> hA (swizzled) ----
      {
        const u64* srcA = (const u64*)(hbuf + ((size_t)(layer * 2 + ((t + 1) & 1)) << 14));
#pragma unroll
        for (int i = tid; i < 4096; i += 1024) {
          u64 v = __hip_atomic_load(&srcA[i], __ATOMIC_RELAXED, __HIP_MEMORY_SCOPE_AGENT);
          int b = i >> 8, k4 = i & 255;                  // k4: u64 within row
          int g = k4 >> 1, hh = k4 & 1;
          *(u64*)&hA[b][((g ^ (b & 7)) << 3) + (hh << 2)] = v;
        }
      }
      // ---- stage prev-layer output -> hB (swizzled) ----
      if (layer == 0) {
#pragma unroll
        for (int i = tid; i < 4096; i += 1024) {
          int b = i >> 8, k4 = i & 255;
          u64 v = *((const u64*)Xbf + ((size_t)(b * Lsz + t) << 8) + k4);
          int g = k4 >> 1, hh = k4 & 1;
          *(u64*)&hB[b][((g ^ (b & 7)) << 3) + (hh << 2)] = v;
        }
      } else {
        const u64* srcB = (const u64*)(hbuf + ((size_t)((layer - 1) * 2 + (t & 1)) << 14));
#pragma unroll
        for (int i = tid; i < 4096; i += 1024) {
          u64 v = __hip_atomic_load(&srcB[i], __ATOMIC_RELAXED, __HIP_MEMORY_SCOPE_AGENT);
          int b = i >> 8, k4 = i & 255;
          int g = k4 >> 1, hh = k4 & 1;
          *(u64*)&hB[b][((g ^ (b & 7)) << 3) + (hh << 2)] = v;
        }
      }
      __syncthreads();

      // ---- MFMA: D[e16][b16] += Wh-slice * h_state + Wx-slice * H_prev ----
      f32x4 acc = {0.f, 0.f, 0.f, 0.f};
#pragma unroll
      for (int s = 0; s < 8; ++s) {
        const int k = klane + s * 32;
        bf16x8 hfrag = *(const bf16x8*)&hA[mrow][((k >> 3) ^ (mrow & 7)) << 3];
        acc = __builtin_amdgcn_mfma_f32_16x16x32_bf16(wfh[s], hfrag, acc, 0, 0, 0);
      }
#pragma unroll
      for (int s = 0; s < 8; ++s) {
        const int k = klane + s * 32;
        bf16x8 hfrag = *(const bf16x8*)&hB[mrow][((k >> 3) ^ (mrow & 7)) << 3];
        acc = __builtin_amdgcn_mfma_f32_16x16x32_bf16(wfx[s], hfrag, acc, 0, 0, 0);
      }
      red[w][lane] = acc;
      __syncthreads();

      // ---- reduce k-split, bias, tanh, publish (waves 0..3) ----
      if (w < 4) {
        f32x4 p = red[w][lane];
        f32x4 q1 = red[w + 4][lane], q2 = red[w + 8][lane], q3 = red[w + 12][lane];
        p.x += q1.x + q2.x + q3.x;  p.y += q1.y + q2.y + q3.y;
        p.z += q1.z + q2.z + q3.z;  p.w += q1.w + q2.w + q3.w;
        const float v0 = tanhf(p.x + bias4.x);
        const float v1 = tanhf(p.y + bias4.y);
        const float v2 = tanhf(p.z + bias4.z);
        const float v3 = tanhf(p.w + bias4.w);
        // publish bf16 h (write-through) — layer 3 needs it for its own recurrence too
        u64 pk = (u64)f2bf(v0) | ((u64)f2bf(v1) << 16) |
                 ((u64)f2bf(v2) << 32) | ((u64)f2bf(v3) << 48);
        u64* hp = (u64*)(hbuf + ((size_t)(layer * 2 + (t & 1)) << 14) + (b_ep << 10) + e_ep);
        __hip_atomic_store(hp, pk, __ATOMIC_RELAXED, __HIP_MEMORY_SCOPE_AGENT);
        if (layer == NL - 1) {
          float4 o = {v0, v1, v2, v3};
          *(float4*)(Hout + ((size_t)(b_ep * Lsz + t) << 10) + e_ep) = o;
        }
      }
    }

    // ---- publish: all this wave's stores at coherence point, then flag ----
    asm volatile("s_waitcnt vmcnt(0)" ::: "memory");
    __syncthreads();
    if (tid == 0)
      __hip_atomic_store(&flags[wg], r, __ATOMIC_RELAXED, __HIP_MEMORY_SCOPE_AGENT);
  }
}

extern "C" void kernel_launch(void* const* d_in, const int* in_sizes, int n_in,
                              void* d_out, int out_size, void* d_ws, size_t ws_size,
                              hipStream_t stream) {
  (void)in_sizes; (void)n_in; (void)out_size; (void)ws_size;
  const float* X0   = (const float*)d_in[0];
  const float* h0s  = (const float*)d_in[1];
  const float* W    = (const float*)d_in[2];
  const float* bias = (const float*)d_in[3];
  float* out = (float*)d_out;
  char* ws = (char*)d_ws;
  // ws: Wbf 16MB | Xbf 16MB | hbuf 256KB | flags
  u16* Wbf  = (u16*)ws;
  u16* Xbf  = (u16*)(ws + 16777216);
  u16* hbuf = (u16*)(ws + 33554432);
  int* flags = (int*)(ws + 33554432 + 262144);

  hipLaunchKernelGGL(convert_bf16_kernel, dim3(2048), dim3(256), 0, stream,
                     W, Wbf, NL * Dsz * 2 * Dsz / 4);
  hipLaunchKernelGGL(convert_bf16_kernel, dim3(2048), dim3(256), 0, stream,
                     X0, Xbf, Bsz * Lsz * Dsz / 4);
  hipLaunchKernelGGL(init_h0_kernel, dim3(64), dim3(256), 0, stream, h0s, hbuf);
  hipLaunchKernelGGL(zero_flags_kernel, dim3(1), dim3(NWG), 0, stream, flags);
  hipLaunchKernelGGL(rnn_persistent, dim3(NWG), dim3(1024), 0, stream,
                     Wbf, Xbf, bias, out, hbuf, flags);
}

// Round 7
// 2478.830 us; speedup vs baseline: 38.6755x; 1.3530x over previous
//
#include <hip/hip_runtime.h>

#define Bsz 16
#define Lsz 512
#define Dsz 1024
#define NL 4
#define NWG 64                    // 4 layers x 16 e-slices
#define NSLOT 8                   // h ring depth per layer (elastic slack)

typedef unsigned short u16;
typedef unsigned long long u64;
typedef __attribute__((ext_vector_type(8))) short bf16x8;
typedef __attribute__((ext_vector_type(4))) float f32x4;

static __device__ __forceinline__ u16 f2bf(float x) {  // RNE, finite inputs
  unsigned u = __float_as_uint(x);
  return (u16)((u + 0x7fffu + ((u >> 16) & 1u)) >> 16);
}

// counters: cnt[l] at flags[l*32] (own 128B line). Monotone: +1 per WG per step.
__global__ void zero_flags_kernel(int* flags) {
  __hip_atomic_store(&flags[threadIdx.x], 0, __ATOMIC_RELAXED, __HIP_MEMORY_SCOPE_AGENT);
}

// flat fp32 -> bf16 (4 elems / iter)
__global__ void convert_bf16_kernel(const float* __restrict__ src, u16* __restrict__ dst, int n4) {
  int i = blockIdx.x * blockDim.x + threadIdx.x;
  int stride = gridDim.x * blockDim.x;
  for (; i < n4; i += stride) {
    float4 v = ((const float4*)src)[i];
    u64 p = (u64)f2bf(v.x) | ((u64)f2bf(v.y) << 16) |
            ((u64)f2bf(v.z) << 32) | ((u64)f2bf(v.w) << 48);
    ((u64*)dst)[i] = p;
  }
}

// h0s[l][b][d] -> hbuf[l][slot=NSLOT-1][b][d]   (t=0 reads slot (t-1)&7 = 7)
__global__ void init_h0_kernel(const float* __restrict__ h0s, u16* __restrict__ hbuf) {
  int i = blockIdx.x * blockDim.x + threadIdx.x;   // 16384 threads, 1 float4 each
  float4 v = ((const float4*)h0s)[i];
  u64 p = (u64)f2bf(v.x) | ((u64)f2bf(v.y) << 16) |
          ((u64)f2bf(v.z) << 32) | ((u64)f2bf(v.w) << 48);
  int l = i >> 12;          // 4096 float4 per layer (16*1024/4)
  int rem = i & 4095;
  ((u64*)hbuf)[(size_t)(l * NSLOT + (NSLOT - 1)) * 4096 + rem] = p;
}

static __device__ __forceinline__ void spin_ge(const int* p, int tgt) {
  while (__hip_atomic_load(p, __ATOMIC_RELAXED, __HIP_MEMORY_SCOPE_AGENT) < tgt) {}
}

// ---------------- persistent pipelined RNN, elastic per-layer sync ----------------
// 64 WGs x 1024 thr. WG wg: layer = wg>>4, e-slice = (wg&15)*64.
// Each WG runs its own t = 0..511 loop (no global rounds). Dependencies via
// per-layer monotone counters cnt[l] (MALL, relaxed atomics):
//   before reading input  hbuf[l-1][t&7]:  cnt[l-1] >= 16*(t+1)
//   before reading state  hbuf[l][(t-1)&7]: cnt[l]   >= 16*t
//   before writing        hbuf[l][t&7]:     cnt[l+1] >= 16*(t-7)   (WAR, 8-slot ring)
// h data through MALL write-through relaxed atomics (round-3-verified protocol):
// producer: h stores -> vmcnt(0) -> syncthreads -> cnt add.
__global__ void __launch_bounds__(1024, 4) rnn_persistent(
    const u16* __restrict__ Wbf,    // [NL][1024][2048]  (cols 0:1024=Wx, 1024:2048=Wh)
    const u16* __restrict__ Xbf,    // [Bsz][Lsz][Dsz]
    const float* __restrict__ bias, // [NL][Dsz]
    float* __restrict__ Hout,       // [Bsz][Lsz][Dsz]  (final layer only)
    u16* hbuf,                      // [NL][NSLOT][Bsz][Dsz]
    int* flags) {
  const int wg = blockIdx.x;
  const int layer = wg >> 4;
  const int e0 = (wg & 15) << 6;
  const int tid = threadIdx.x;
  const int w = tid >> 6;          // wave 0..15
  const int lane = tid & 63;
  const int kq = w >> 2;           // k-quarter (256 d)
  const int nt = w & 3;            // n-subtile (16 e)

  __shared__ u16 hA[16][1024];     // h_state   (XOR-swizzled 16B granules)
  __shared__ u16 hB[16][1024];     // prev-layer output (or X)
  __shared__ f32x4 red[16][64];    // k-split partials

  // ---- preload W fragments into VGPRs (time-invariant) ----
  bf16x8 wfh[8], wfx[8];
  {
    const int e = e0 + nt * 16 + (lane & 15);
    const u16* baseW = Wbf + ((size_t)((layer << 10) + e) << 11)
                       + kq * 256 + ((lane >> 4) << 3);
#pragma unroll
    for (int s = 0; s < 8; ++s) {
      wfx[s] = *(const bf16x8*)(baseW + s * 32);          // Wx
      wfh[s] = *(const bf16x8*)(baseW + 1024 + s * 32);   // Wh
    }
  }
  const int b_ep = lane & 15;
  const int e_ep = e0 + w * 16 + ((lane >> 4) << 2);
  float4 bias4 = {0.f, 0.f, 0.f, 0.f};
  if (w < 4) bias4 = *(const float4*)(bias + (layer << 10) + e_ep);

  const int klane = kq * 256 + ((lane >> 4) << 3);
  const int mrow = lane & 15;

  const int* cnt_up   = flags + (layer - 1) * 32;   // valid if layer>0
  const int* cnt_own  = flags + layer * 32;
  const int* cnt_down = flags + (layer + 1) * 32;   // valid if layer<NL-1
  int* cnt_mine = flags + layer * 32;

  for (int t = 0; t < Lsz; ++t) {
    // ---- phase A: wait upstream done step t, then stage hB (input) ----
    if (layer > 0) {
      if (tid < 64) spin_ge(cnt_up, 16 * (t + 1));
      __syncthreads();
      const u64* srcB = (const u64*)(hbuf + ((size_t)((layer - 1) * NSLOT + (t & 7)) << 14));
#pragma unroll
      for (int i = tid; i < 4096; i += 1024) {
        u64 v = __hip_atomic_load(&srcB[i], __ATOMIC_RELAXED, __HIP_MEMORY_SCOPE_AGENT);
        int b = i >> 8, k4 = i & 255;
        int g = k4 >> 1, hh = k4 & 1;
        *(u64*)&hB[b][((g ^ (b & 7)) << 3) + (hh << 2)] = v;
      }
    } else {
#pragma unroll
      for (int i = tid; i < 4096; i += 1024) {
        int b = i >> 8, k4 = i & 255;
        u64 v = *((const u64*)Xbf + ((size_t)(b * Lsz + t) << 8) + k4);
        int g = k4 >> 1, hh = k4 & 1;
        *(u64*)&hB[b][((g ^ (b & 7)) << 3) + (hh << 2)] = v;
      }
    }

    // ---- phase B: own layer done t-1 (h_state ready) + WAR on slot t&7 ----
    if (tid < 64) {
      if (t > 0) spin_ge(cnt_own, 16 * t);
      if (layer < NL - 1 && t >= NSLOT) spin_ge(cnt_down, 16 * (t - (NSLOT - 1)));
    }
    __syncthreads();
    {
      const u64* srcA = (const u64*)(hbuf + ((size_t)(layer * NSLOT + ((t + NSLOT - 1) & 7)) << 14));
#pragma unroll
      for (int i = tid; i < 4096; i += 1024) {
        u64 v = __hip_atomic_load(&srcA[i], __ATOMIC_RELAXED, __HIP_MEMORY_SCOPE_AGENT);
        int b = i >> 8, k4 = i & 255;
        int g = k4 >> 1, hh = k4 & 1;
        *(u64*)&hA[b][((g ^ (b & 7)) << 3) + (hh << 2)] = v;
      }
    }
    __syncthreads();

    // ---- MFMA: D[e16][b16] += Wh*h_state + Wx*input ----
    f32x4 acc = {0.f, 0.f, 0.f, 0.f};
#pragma unroll
    for (int s = 0; s < 8; ++s) {
      const int k = klane + s * 32;
      bf16x8 hfrag = *(const bf16x8*)&hA[mrow][((k >> 3) ^ (mrow & 7)) << 3];
      acc = __builtin_amdgcn_mfma_f32_16x16x32_bf16(wfh[s], hfrag, acc, 0, 0, 0);
    }
#pragma unroll
    for (int s = 0; s < 8; ++s) {
      const int k = klane + s * 32;
      bf16x8 hfrag = *(const bf16x8*)&hB[mrow][((k >> 3) ^ (mrow & 7)) << 3];
      acc = __builtin_amdgcn_mfma_f32_16x16x32_bf16(wfx[s], hfrag, acc, 0, 0, 0);
    }
    red[w][lane] = acc;
    __syncthreads();

    // ---- reduce k-split, bias, tanh, publish h (waves 0..3) ----
    float v0 = 0.f, v1 = 0.f, v2 = 0.f, v3 = 0.f;
    if (w < 4) {
      f32x4 p = red[w][lane];
      f32x4 q1 = red[w + 4][lane], q2 = red[w + 8][lane], q3 = red[w + 12][lane];
      p.x += q1.x + q2.x + q3.x;  p.y += q1.y + q2.y + q3.y;
      p.z += q1.z + q2.z + q3.z;  p.w += q1.w + q2.w + q3.w;
      v0 = tanhf(p.x + bias4.x);
      v1 = tanhf(p.y + bias4.y);
      v2 = tanhf(p.z + bias4.z);
      v3 = tanhf(p.w + bias4.w);
      u64 pk = (u64)f2bf(v0) | ((u64)f2bf(v1) << 16) |
               ((u64)f2bf(v2) << 32) | ((u64)f2bf(v3) << 48);
      u64* hp = (u64*)(hbuf + ((size_t)(layer * NSLOT + (t & 7)) << 14) + (b_ep << 10) + e_ep);
      __hip_atomic_store(hp, pk, __ATOMIC_RELAXED, __HIP_MEMORY_SCOPE_AGENT);
    }

    // ---- publish: h stores at coherence point, then counter add ----
    asm volatile("s_waitcnt vmcnt(0)" ::: "memory");
    __syncthreads();
    if (tid == 0)
      __hip_atomic_fetch_add(cnt_mine, 1, __ATOMIC_RELAXED, __HIP_MEMORY_SCOPE_AGENT);

    // ---- layer-3 output store AFTER publish (HBM ack off critical path) ----
    if (layer == NL - 1 && w < 4) {
      float4 o = {v0, v1, v2, v3};
      *(float4*)(Hout + ((size_t)(b_ep * Lsz + t) << 10) + e_ep) = o;
    }
  }
}

extern "C" void kernel_launch(void* const* d_in, const int* in_sizes, int n_in,
                              void* d_out, int out_size, void* d_ws, size_t ws_size,
                              hipStream_t stream) {
  (void)in_sizes; (void)n_in; (void)out_size; (void)ws_size;
  const float* X0   = (const float*)d_in[0];
  const float* h0s  = (const float*)d_in[1];
  const float* W    = (const float*)d_in[2];
  const float* bias = (const float*)d_in[3];
  float* out = (float*)d_out;
  char* ws = (char*)d_ws;
  // ws: Wbf 16MB | Xbf 16MB | hbuf 1MB (4 layers x 8 slots x 32KB) | flags 512B
  u16* Wbf  = (u16*)ws;
  u16* Xbf  = (u16*)(ws + 16777216);
  u16* hbuf = (u16*)(ws + 33554432);
  int* flags = (int*)(ws + 33554432 + 1048576);

  hipLaunchKernelGGL(convert_bf16_kernel, dim3(2048), dim3(256), 0, stream,
                     W, Wbf, NL * Dsz * 2 * Dsz / 4);
  hipLaunchKernelGGL(convert_bf16_kernel, dim3(2048), dim3(256), 0, stream,
                     X0, Xbf, Bsz * Lsz * Dsz / 4);
  hipLaunchKernelGGL(init_h0_kernel, dim3(64), dim3(256), 0, stream, h0s, hbuf);
  hipLaunchKernelGGL(zero_flags_kernel, dim3(1), dim3(128), 0, stream, flags);
  hipLaunchKernelGGL(rnn_persistent, dim3(NWG), dim3(1024), 0, stream,
                     Wbf, Xbf, bias, out, hbuf, flags);
}